// Round 9
// baseline (190.899 us; speedup 1.0000x reference)
//
#include <hip/hip_runtime.h>

#define TT 512
#define BB 512
#define NN 64
#define LN2F 0.69314718055994530942f

typedef _Float16 half8_t __attribute__((ext_vector_type(8)));
typedef float    f32x4   __attribute__((ext_vector_type(4)));

union AFrag { int u[4]; half8_t h; };

__device__ __forceinline__ float wave_max(float v) {
    #pragma unroll
    for (int off = 32; off > 0; off >>= 1)
        v = fmaxf(v, __shfl_xor(v, off, 64));
    return v;
}

__device__ __forceinline__ float wave_sum(float v) {
    #pragma unroll
    for (int off = 32; off > 0; off >>= 1)
        v += __shfl_xor(v, off, 64);
    return v;
}

__device__ __forceinline__ int wave_sum_i(int v) {
    #pragma unroll
    for (int off = 32; off > 0; off >>= 1)
        v += __shfl_xor(v, off, 64);
    return v;
}

__device__ __forceinline__ float bcast_lane(float v, int lane) {
    return __uint_as_float(__builtin_amdgcn_readlane(__float_as_uint(v), lane));
}

// async global->LDS DMA, 4 bytes/lane: LDS dest = uniform base + lane*4.
__device__ __forceinline__ void async4(const float* g, float* l) {
    __builtin_amdgcn_global_load_lds(
        (const __attribute__((address_space(1))) unsigned int*)g,
        (__attribute__((address_space(3))) unsigned int*)l,
        4, 0, 0);
}

// Zero the scalar output (harness poisons d_out with 0xAA before every launch).
__global__ void zero_kernel(float* __restrict__ out) {
    if (threadIdx.x == 0 && blockIdx.x == 0) out[0] = 0.0f;
}

// Forward algorithm in the EXP domain, matvec via MFMA, emit staged through a
// 2-half LDS ring (global_load_lds DMA — r8 win: 177->103 us).
// r8 post-mortem: step ~483 cyc; the 8 ds_bpermute gather ops are ~8 in-order
// LDS-pipe slots on the critical chain. This round replaces them with
// 1 ds_write_b32 + 2 ds_read_b128: lane L's A-fragment (K-half h) is the 16
// CONTIGUOUS bytes pairs[16h+4q .. 16h+4q+3] of the packed-f16 u vector, so a
// broadcast b128 read per half suffices (conflict-free: 4 addrs span 16 banks).
// Write->read ordering: in-order per-wave LDS pipe + same-array aliasing.
__global__ __launch_bounds__(64) void crf_fwd_kernel(
    const float* __restrict__ emit,
    const float* __restrict__ trans,
    const float* __restrict__ strans,
    const float* __restrict__ etrans,
    const int*   __restrict__ target,
    const void*  __restrict__ maskp,
    float* __restrict__ out)
{
    const int b = blockIdx.x;
    const int k = threadIdx.x;

    __shared__ float sem[2][8][NN];                    // 4 KB emit ring
    __shared__ __align__(16) unsigned int upck[32];    // u as 32 packed f16 pairs

    const int*           mi32 = (const int*)maskp;
    const unsigned char* mi8  = (const unsigned char*)maskp;
    // mask[0,:] is all-true (lengths >= 1): byte encoding -> word0 == 0x01010101.
    const bool bytemode = (mi32[0] == 0x01010101);

    // len[b] = sum_t mask[t,b] (mask monotone per column) — one-time cost.
    int cnt = 0;
    #pragma unroll
    for (int i = 0; i < TT / 64; ++i) {
        const size_t tb = (size_t)(i * 64 + k) * BB + b;
        cnt += bytemode ? (mi8[tb] != 0) : (mi32[tb] != 0);
    }
    const int len = wave_sum_i(cnt);   // wave-uniform

    const int q   = k >> 4;
    const int nlo = k & 15;
    const bool odd  = (k & 1)  != 0;
    const bool bit4 = (k & 16) != 0;
    const bool bit5 = (k & 32) != 0;

    const float* ecol = emit + (size_t)b * NN + k;   // row stride BB*NN

    // Prologue: DMA rows 1..8 into half 0 (rows 1..8 always exist: TT=512).
    #pragma unroll
    for (int s = 0; s < 8; ++s)
        async4(ecol + (size_t)(1 + s) * BB * NN, &sem[0][s][0]);

    // B fragments: Bf[g][kh], element j = 0.25*exp(trans[(32kh+8q+j)][16g+nlo]).
    // A-layout: A[m=lane&15][k2=8*(lane>>4)+j]; all 16 A-rows replicated with u.
    // C/D: col=lane&15, all rows equal -> lane k selects group k>>4 via cndmasks.
    half8_t Bf[4][2];
    #pragma unroll
    for (int g = 0; g < 4; ++g) {
        #pragma unroll
        for (int kh = 0; kh < 2; ++kh) {
            AFrag bf;
            #pragma unroll
            for (int jp = 0; jp < 4; ++jp) {
                const int krow = 32 * kh + 8 * q + 2 * jp;
                const float e0 = 0.25f * __expf(trans[(krow + 0) * NN + 16 * g + nlo]);
                const float e1 = 0.25f * __expf(trans[(krow + 1) * NN + 16 * g + nlo]);
                bf.u[jp] = __builtin_bit_cast(int, __builtin_amdgcn_cvt_pkrtz(e0, e1));
            }
            Bf[g][kh] = bf.h;
        }
    }

    const f32x4 zero4 = {0.f, 0.f, 0.f, 0.f};

    // t = 0: u = exp(alpha0 - m0)
    const float alpha0 = ecol[0] + strans[k];
    const float m0 = bcast_lane(alpha0, 0);
    float u = __expf(alpha0 - m0);
    int e_sum = 0;

    // One exp-domain step: u' = ldexp((u . 0.25E) * wloc, -e); e_sum += e+2.
    auto do_step = [&](float wloc) {
        // pack f16 pair (u_{2m}, u_{2m+1}) via DPP quad_perm(1,0,3,2) = xor-1.
        const float uo = __int_as_float(
            __builtin_amdgcn_mov_dpp(__float_as_int(u), 0xB1, 0xF, 0xF, true));
        const float pe = odd ? uo : u;
        const float po = odd ? u : uo;
        const unsigned int pkv =
            __builtin_bit_cast(unsigned int, __builtin_amdgcn_cvt_pkrtz(pe, po));

        // publish pair m = k>>1 (lanes 2m and 2m+1 write identical data),
        // then gather both A-fragments as contiguous 16B broadcast reads.
        upck[k >> 1] = pkv;
        AFrag a0f, a1f;
        const int4 lo = *(const int4*)&upck[4 * q];        // pairs 4q..4q+3
        const int4 hi = *(const int4*)&upck[16 + 4 * q];   // pairs 16+4q..
        a0f.u[0] = lo.x; a0f.u[1] = lo.y; a0f.u[2] = lo.z; a0f.u[3] = lo.w;
        a1f.u[0] = hi.x; a1f.u[1] = hi.y; a1f.u[2] = hi.z; a1f.u[3] = hi.w;

        const f32x4 accA0 = __builtin_amdgcn_mfma_f32_16x16x32_f16(a0f.h, Bf[0][0], zero4, 0, 0, 0);
        const f32x4 accA1 = __builtin_amdgcn_mfma_f32_16x16x32_f16(a0f.h, Bf[1][0], zero4, 0, 0, 0);
        const f32x4 accA2 = __builtin_amdgcn_mfma_f32_16x16x32_f16(a0f.h, Bf[2][0], zero4, 0, 0, 0);
        const f32x4 accA3 = __builtin_amdgcn_mfma_f32_16x16x32_f16(a0f.h, Bf[3][0], zero4, 0, 0, 0);
        const f32x4 accB0 = __builtin_amdgcn_mfma_f32_16x16x32_f16(a1f.h, Bf[0][1], zero4, 0, 0, 0);
        const f32x4 accB1 = __builtin_amdgcn_mfma_f32_16x16x32_f16(a1f.h, Bf[1][1], zero4, 0, 0, 0);
        const f32x4 accB2 = __builtin_amdgcn_mfma_f32_16x16x32_f16(a1f.h, Bf[2][1], zero4, 0, 0, 0);
        const f32x4 accB3 = __builtin_amdgcn_mfma_f32_16x16x32_f16(a1f.h, Bf[3][1], zero4, 0, 0, 0);

        const float sAlo = bit4 ? accA1[0] : accA0[0];
        const float sAhi = bit4 ? accA3[0] : accA2[0];
        const float sBlo = bit4 ? accB1[0] : accB0[0];
        const float sBhi = bit4 ? accB3[0] : accB2[0];
        const float y = ((bit5 ? sAhi : sAlo) + (bit5 ? sBhi : sBlo)) * wloc;

        // power-of-2 rescale from lane0's exponent; +2 restores the 2^-2
        // folded into the B fragments (exact bookkeeping).
        const int e = (int)((__builtin_amdgcn_readfirstlane(__float_as_uint(y)) >> 23) & 0xff) - 127;
        u = ldexpf(y, -e);
        e_sum += e + 2;
    };

    int t = 1;
    int half = 0;
    // Invariant at block top: rows t..t+7 are in sem[half][0..7] — their DMAs
    // were issued >= 1 block (~8 steps) ago, so the vmcnt wait is free.
    for (; t + 8 <= len; t += 8) {
        // (1) read this block's rows into registers
        float v0 = sem[half][0][k], v1 = sem[half][1][k];
        float v2 = sem[half][2][k], v3 = sem[half][3][k];
        float v4 = sem[half][4][k], v5 = sem[half][5][k];
        float v6 = sem[half][6][k], v7 = sem[half][7][k];

        // (2) issue next block's DMAs into the other half (clamped at TT-1;
        //     overshoot rows are never consumed)
        #pragma unroll
        for (int s = 0; s < 8; ++s) {
            const int tf = (t + 8 + s < TT) ? (t + 8 + s) : (TT - 1);
            async4(ecol + (size_t)tf * BB * NN, &sem[half ^ 1][s][0]);
        }

        // (3) exps off the u-chain, then 8 MFMA steps
        const float w0 = __expf(v0), w1 = __expf(v1), w2 = __expf(v2), w3 = __expf(v3);
        const float w4 = __expf(v4), w5 = __expf(v5), w6 = __expf(v6), w7 = __expf(v7);
        do_step(w0); do_step(w1); do_step(w2); do_step(w3);
        do_step(w4); do_step(w5); do_step(w6); do_step(w7);

        half ^= 1;
    }

    // Remainder (< 8 steps): rows t..len-1 are already in sem[half][...].
    for (int s = 0; t < len; ++t, ++s)
        do_step(__expf(sem[half][s][k]));

    // logZ_b = S + logsumexp_k(log(u_k) + etrans[k]),  S = m0 + ln2*e_sum
    const float la = __logf(u) + etrans[k];   // u==0 -> -inf -> exp -> 0: fine
    const float m2 = wave_max(la);
    const float sm = wave_sum(__expf(la - m2));
    const float logZ_b = m0 + LN2F * (float)e_sum + m2 + __logf(sm);

    // ---- fused gold score for batch b: lane k covers t = 64*i + k ----
    int tvals[TT / 64];
    #pragma unroll
    for (int i = 0; i < TT / 64; ++i)
        tvals[i] = target[(size_t)(64 * i + k) * BB + b];

    float g = 0.f;
    int prev_last = 0;
    #pragma unroll
    for (int i = 0; i < TT / 64; ++i) {
        const int tt = 64 * i + k;
        const int tgt = tvals[i];
        int tprev = __shfl_up(tvals[i], 1, 64);
        if (k == 0) tprev = prev_last;                       // carry across i
        prev_last = __builtin_amdgcn_readlane(tvals[i], 63);
        if (tt < len) {
            float v = emit[((size_t)tt * BB + b) * NN + tgt];
            v += (tt == 0) ? strans[tgt] : trans[tprev * NN + tgt];
            if (tt == len - 1) v += etrans[tgt];
            g += v;
        }
    }
    g = wave_sum(g);

    if (k == 0) atomicAdd(out, logZ_b - g);
}

extern "C" void kernel_launch(void* const* d_in, const int* in_sizes, int n_in,
                              void* d_out, int out_size, void* d_ws, size_t ws_size,
                              hipStream_t stream) {
    const float* emit   = (const float*)d_in[0];
    const float* trans  = (const float*)d_in[1];
    const float* strans = (const float*)d_in[2];
    const float* etrans = (const float*)d_in[3];
    const int*   target = (const int*)d_in[4];
    const void*  mask   = d_in[5];
    float* out = (float*)d_out;

    hipLaunchKernelGGL(zero_kernel, dim3(1), dim3(64), 0, stream, out);
    hipLaunchKernelGGL(crf_fwd_kernel, dim3(BB), dim3(64), 0, stream,
                       emit, trans, strans, etrans, target, mask, out);
}

// Round 10
// 185.732 us; speedup vs baseline: 1.0278x; 1.0278x over previous
//
#include <hip/hip_runtime.h>

#define TT 512
#define BB 512
#define NN 64
#define LN2F 0.69314718055994530942f

typedef _Float16 half8_t __attribute__((ext_vector_type(8)));
typedef float    f32x4   __attribute__((ext_vector_type(4)));

union AFrag { int u[4]; half8_t h; };

__device__ __forceinline__ float wave_max(float v) {
    #pragma unroll
    for (int off = 32; off > 0; off >>= 1)
        v = fmaxf(v, __shfl_xor(v, off, 64));
    return v;
}

__device__ __forceinline__ float wave_sum(float v) {
    #pragma unroll
    for (int off = 32; off > 0; off >>= 1)
        v += __shfl_xor(v, off, 64);
    return v;
}

__device__ __forceinline__ int wave_sum_i(int v) {
    #pragma unroll
    for (int off = 32; off > 0; off >>= 1)
        v += __shfl_xor(v, off, 64);
    return v;
}

__device__ __forceinline__ float bcast_lane(float v, int lane) {
    return __uint_as_float(__builtin_amdgcn_readlane(__float_as_uint(v), lane));
}

// async global->LDS DMA, 4 bytes/lane: LDS dest = uniform base + lane*4.
__device__ __forceinline__ void async4(const float* g, float* l) {
    __builtin_amdgcn_global_load_lds(
        (const __attribute__((address_space(1))) unsigned int*)g,
        (__attribute__((address_space(3))) unsigned int*)l,
        4, 0, 0);
}

// Zero the scalar output (harness poisons d_out with 0xAA before every launch).
__global__ void zero_kernel(float* __restrict__ out) {
    if (threadIdx.x == 0 && blockIdx.x == 0) out[0] = 0.0f;
}

// Forward algorithm in the EXP domain, matvec via MFMA, emit staged through a
// 2-half LDS ring (global_load_lds DMA — r8 win: 177->103 us).
// r9 post-mortem: write+2xb128 gather was slightly WORSE than 8 bpermutes
// (LDS latency, not op count, is what the chain pays). Chain model:
// LDS gather ~130 + MFMA pipe 8x19.4 ~155 + VALU tail ~90 + hazards ~ 420-450.
// This round: (1) revert to bpermute gather; (2) chain K-halves through the
// MFMA C operand (pipe is serial anyway; 78-cyc spacing >= result latency)
// which cuts the epilogue select from 6 cndmask + 1 add to 3 cndmask.
__global__ __launch_bounds__(64) void crf_fwd_kernel(
    const float* __restrict__ emit,
    const float* __restrict__ trans,
    const float* __restrict__ strans,
    const float* __restrict__ etrans,
    const int*   __restrict__ target,
    const void*  __restrict__ maskp,
    float* __restrict__ out)
{
    const int b = blockIdx.x;
    const int k = threadIdx.x;

    __shared__ float sem[2][8][NN];   // 4 KB emit ring: [half][slot][state]

    const int*           mi32 = (const int*)maskp;
    const unsigned char* mi8  = (const unsigned char*)maskp;
    // mask[0,:] is all-true (lengths >= 1): byte encoding -> word0 == 0x01010101.
    const bool bytemode = (mi32[0] == 0x01010101);

    // len[b] = sum_t mask[t,b] (mask monotone per column) — one-time cost.
    int cnt = 0;
    #pragma unroll
    for (int i = 0; i < TT / 64; ++i) {
        const size_t tb = (size_t)(i * 64 + k) * BB + b;
        cnt += bytemode ? (mi8[tb] != 0) : (mi32[tb] != 0);
    }
    const int len = wave_sum_i(cnt);   // wave-uniform

    const int q   = k >> 4;
    const int nlo = k & 15;
    const bool odd  = (k & 1)  != 0;
    const bool bit4 = (k & 16) != 0;
    const bool bit5 = (k & 32) != 0;

    const float* ecol = emit + (size_t)b * NN + k;   // row stride BB*NN

    // Prologue: DMA rows 1..8 into half 0 (rows 1..8 always exist: TT=512).
    #pragma unroll
    for (int s = 0; s < 8; ++s)
        async4(ecol + (size_t)(1 + s) * BB * NN, &sem[0][s][0]);

    // B fragments: Bf[g][kh], element j = 0.25*exp(trans[(32kh+8q+j)][16g+nlo]).
    // A-layout: A[m=lane&15][k2=8*(lane>>4)+j]; all 16 A-rows replicated with u.
    // C/D: col=lane&15, all rows equal -> lane k selects group k>>4 via cndmasks.
    half8_t Bf[4][2];
    #pragma unroll
    for (int g = 0; g < 4; ++g) {
        #pragma unroll
        for (int kh = 0; kh < 2; ++kh) {
            AFrag bf;
            #pragma unroll
            for (int jp = 0; jp < 4; ++jp) {
                const int krow = 32 * kh + 8 * q + 2 * jp;
                const float e0 = 0.25f * __expf(trans[(krow + 0) * NN + 16 * g + nlo]);
                const float e1 = 0.25f * __expf(trans[(krow + 1) * NN + 16 * g + nlo]);
                bf.u[jp] = __builtin_bit_cast(int, __builtin_amdgcn_cvt_pkrtz(e0, e1));
            }
            Bf[g][kh] = bf.h;
        }
    }

    // bpermute byte-addresses: A frag (kh, reg r) needs the f16 pair
    // (u_{32kh+8q+2r}, u_{...+2r+1}), held by source lane 32kh+8q+2r.
    int addrs[8];
    #pragma unroll
    for (int kh = 0; kh < 2; ++kh)
        #pragma unroll
        for (int r = 0; r < 4; ++r)
            addrs[4 * kh + r] = 128 * kh + 32 * q + 8 * r;

    const f32x4 zero4 = {0.f, 0.f, 0.f, 0.f};

    // t = 0: u = exp(alpha0 - m0)
    const float alpha0 = ecol[0] + strans[k];
    const float m0 = bcast_lane(alpha0, 0);
    float u = __expf(alpha0 - m0);
    int e_sum = 0;

    // One exp-domain step: u' = ldexp((u . 0.25E) * wloc, -e); e_sum += e+2.
    auto do_step = [&](float wloc) {
        // pack f16 pair (u_{2m}, u_{2m+1}) via DPP quad_perm(1,0,3,2) = xor-1.
        const float uo = __int_as_float(
            __builtin_amdgcn_mov_dpp(__float_as_int(u), 0xB1, 0xF, 0xF, true));
        const float pe = odd ? uo : u;
        const float po = odd ? u : uo;
        const int pkv = __builtin_bit_cast(int, __builtin_amdgcn_cvt_pkrtz(pe, po));

        // gather A fragments (8 bpermutes, in-order LDS pipe)
        AFrag a0f, a1f;
        #pragma unroll
        for (int r = 0; r < 4; ++r) {
            a0f.u[r] = __builtin_amdgcn_ds_bpermute(addrs[r],     pkv);
            a1f.u[r] = __builtin_amdgcn_ds_bpermute(addrs[4 + r], pkv);
        }

        // y = u * 0.25E : 4 column groups; K-halves chained through C.
        // (pipe-serial MFMAs: by the time accB_g issues, accA_g has retired)
        const f32x4 accA0 = __builtin_amdgcn_mfma_f32_16x16x32_f16(a0f.h, Bf[0][0], zero4, 0, 0, 0);
        const f32x4 accA1 = __builtin_amdgcn_mfma_f32_16x16x32_f16(a0f.h, Bf[1][0], zero4, 0, 0, 0);
        const f32x4 accA2 = __builtin_amdgcn_mfma_f32_16x16x32_f16(a0f.h, Bf[2][0], zero4, 0, 0, 0);
        const f32x4 accA3 = __builtin_amdgcn_mfma_f32_16x16x32_f16(a0f.h, Bf[3][0], zero4, 0, 0, 0);
        const f32x4 acc0 = __builtin_amdgcn_mfma_f32_16x16x32_f16(a1f.h, Bf[0][1], accA0, 0, 0, 0);
        const f32x4 acc1 = __builtin_amdgcn_mfma_f32_16x16x32_f16(a1f.h, Bf[1][1], accA1, 0, 0, 0);
        const f32x4 acc2 = __builtin_amdgcn_mfma_f32_16x16x32_f16(a1f.h, Bf[2][1], accA2, 0, 0, 0);
        const f32x4 acc3 = __builtin_amdgcn_mfma_f32_16x16x32_f16(a1f.h, Bf[3][1], accA3, 0, 0, 0);

        // lane k takes column-group g = k>>4 (all D rows identical): 3 cndmasks
        const float sLo = bit4 ? acc1[0] : acc0[0];
        const float sHi = bit4 ? acc3[0] : acc2[0];
        const float y = (bit5 ? sHi : sLo) * wloc;

        // power-of-2 rescale from lane0's exponent; +2 restores the 2^-2
        // folded into the B fragments (exact bookkeeping).
        const int e = (int)((__builtin_amdgcn_readfirstlane(__float_as_uint(y)) >> 23) & 0xff) - 127;
        u = ldexpf(y, -e);
        e_sum += e + 2;
    };

    int t = 1;
    int half = 0;
    // Invariant at block top: rows t..t+7 are in sem[half][0..7] — their DMAs
    // were issued >= 1 block (~8 steps) ago, so the vmcnt wait is free.
    for (; t + 8 <= len; t += 8) {
        // (1) read this block's rows into registers (off the u-chain)
        float v0 = sem[half][0][k], v1 = sem[half][1][k];
        float v2 = sem[half][2][k], v3 = sem[half][3][k];
        float v4 = sem[half][4][k], v5 = sem[half][5][k];
        float v6 = sem[half][6][k], v7 = sem[half][7][k];

        // (2) issue next block's DMAs into the other half (clamped at TT-1;
        //     overshoot rows are never consumed)
        #pragma unroll
        for (int s = 0; s < 8; ++s) {
            const int tf = (t + 8 + s < TT) ? (t + 8 + s) : (TT - 1);
            async4(ecol + (size_t)tf * BB * NN, &sem[half ^ 1][s][0]);
        }

        // (3) exps off the u-chain, then 8 MFMA steps
        const float w0 = __expf(v0), w1 = __expf(v1), w2 = __expf(v2), w3 = __expf(v3);
        const float w4 = __expf(v4), w5 = __expf(v5), w6 = __expf(v6), w7 = __expf(v7);
        do_step(w0); do_step(w1); do_step(w2); do_step(w3);
        do_step(w4); do_step(w5); do_step(w6); do_step(w7);

        half ^= 1;
    }

    // Remainder (< 8 steps): rows t..len-1 are already in sem[half][...].
    for (int s = 0; t < len; ++t, ++s)
        do_step(__expf(sem[half][s][k]));

    // logZ_b = S + logsumexp_k(log(u_k) + etrans[k]),  S = m0 + ln2*e_sum
    const float la = __logf(u) + etrans[k];   // u==0 -> -inf -> exp -> 0: fine
    const float m2 = wave_max(la);
    const float sm = wave_sum(__expf(la - m2));
    const float logZ_b = m0 + LN2F * (float)e_sum + m2 + __logf(sm);

    // ---- fused gold score for batch b: lane k covers t = 64*i + k ----
    int tvals[TT / 64];
    #pragma unroll
    for (int i = 0; i < TT / 64; ++i)
        tvals[i] = target[(size_t)(64 * i + k) * BB + b];

    float g = 0.f;
    int prev_last = 0;
    #pragma unroll
    for (int i = 0; i < TT / 64; ++i) {
        const int tt = 64 * i + k;
        const int tgt = tvals[i];
        int tprev = __shfl_up(tvals[i], 1, 64);
        if (k == 0) tprev = prev_last;                       // carry across i
        prev_last = __builtin_amdgcn_readlane(tvals[i], 63);
        if (tt < len) {
            float v = emit[((size_t)tt * BB + b) * NN + tgt];
            v += (tt == 0) ? strans[tgt] : trans[tprev * NN + tgt];
            if (tt == len - 1) v += etrans[tgt];
            g += v;
        }
    }
    g = wave_sum(g);

    if (k == 0) atomicAdd(out, logZ_b - g);
}

extern "C" void kernel_launch(void* const* d_in, const int* in_sizes, int n_in,
                              void* d_out, int out_size, void* d_ws, size_t ws_size,
                              hipStream_t stream) {
    const float* emit   = (const float*)d_in[0];
    const float* trans  = (const float*)d_in[1];
    const float* strans = (const float*)d_in[2];
    const float* etrans = (const float*)d_in[3];
    const int*   target = (const int*)d_in[4];
    const void*  mask   = d_in[5];
    float* out = (float*)d_out;

    hipLaunchKernelGGL(zero_kernel, dim3(1), dim3(64), 0, stream, out);
    hipLaunchKernelGGL(crf_fwd_kernel, dim3(BB), dim3(64), 0, stream,
                       emit, trans, strans, etrans, target, mask, out);
}